// Round 5
// baseline (240.452 us; speedup 1.0000x reference)
//
#include <hip/hip_runtime.h>
#include <hip/hip_bf16.h>

typedef __attribute__((ext_vector_type(8))) short bf16x8;
typedef __attribute__((ext_vector_type(4))) float f32x4;
typedef __attribute__((ext_vector_type(4))) float f4v;
typedef __attribute__((ext_vector_type(4))) short s4v;

__device__ __forceinline__ short f2bf(float f) {
    union { __hip_bfloat16 h; short s; } u;
    u.h = __float2bfloat16(f);
    return u.s;
}

__device__ __forceinline__ void gload_lds16(const void* g, void* l) {
    __builtin_amdgcn_global_load_lds(
        (const __attribute__((address_space(1))) void*)g,
        (__attribute__((address_space(3))) void*)l,
        16, 0, 0);
}

#define MFMA16(a, b, c) __builtin_amdgcn_mfma_f32_16x16x32_bf16((a), (b), (c), 0, 0, 0)

// ---------------- fused prep: 3x f32->bf16 cvt + per-batch scale ----------------
__global__ void prep_kernel(const float* __restrict__ x,
                            const float* __restrict__ qw,
                            const float* __restrict__ ow,
                            const float* __restrict__ pd,
                            const float* __restrict__ alphap,
                            s4v* __restrict__ xb, s4v* __restrict__ qb,
                            s4v* __restrict__ ob, float* __restrict__ scales) {
    __shared__ float wsum[4];
    if (blockIdx.x >= 2048) {
        int b = blockIdx.x - 2048;
        float s = 0.f;
        for (int i = threadIdx.x; i < 2048; i += 256) s += pd[b * 2048 + i];
        for (int o = 32; o; o >>= 1) s += __shfl_down(s, o);
        if ((threadIdx.x & 63) == 0) wsum[threadIdx.x >> 6] = s;
        __syncthreads();
        if (threadIdx.x == 0) {
            float t = wsum[0] + wsum[1] + wsum[2] + wsum[3];
            float mean = t * (1.0f / 2048.0f);
            float temp = fmaxf(1.0f + alphap[0] * mean, 1e-6f);
            scales[b] = 0.125f * temp;
        }
        return;
    }
    #pragma unroll
    for (int j = 0; j < 4; ++j) {
        int idx = blockIdx.x * 1024 + j * 256 + threadIdx.x;
        const f4v* src;
        s4v* dst;
        int off;
        if (idx < 1048576)      { src = (const f4v*)x;  dst = xb; off = idx; }
        else if (idx < 1835008) { src = (const f4v*)qw; dst = qb; off = idx - 1048576; }
        else                    { src = (const f4v*)ow; dst = ob; off = idx - 1835008; }
        f4v v = src[off];
        s4v o;
        #pragma unroll
        for (int k = 0; k < 4; ++k) o[k] = f2bf(v[k]);
        dst[off] = o;
    }
}

// ---------------- QKV GEMM: 256x256 tile, BK=32, 3-deep pipeline, 8 waves ----
__global__ __launch_bounds__(512, 2)
void gemm_qkv_8ph(const __hip_bfloat16* __restrict__ A,
                  const __hip_bfloat16* __restrict__ Bw,
                  const float* __restrict__ bias,
                  __hip_bfloat16* __restrict__ C) {
    extern __shared__ short lds[];
    const int tid = threadIdx.x;
    const int wave = tid >> 6, lane = tid & 63;
    const int g = lane >> 4, c = lane & 15;
    const int wr = wave >> 2, wc = wave & 3;

    int bid = blockIdx.y * 12 + blockIdx.x;
    bid = (bid & 7) * 24 + (bid >> 3);          // XCD swizzle, 192 % 8 == 0
    const long m0 = (long)(bid / 12) * 256;
    const long n0 = (long)(bid % 12) * 256;

    const int sr = tid >> 3;
    const int ss = tid & 7;
    const int sl = ss ^ (sr & 7);
    const int srowoff = 2 * sr + (sl >> 2);
    const int skel = (sl & 3) * 8;

    const int xterm = (((c & 1) << 6) | (g << 4)) ^ ((c >> 1) << 4);

    f32x4 acc[8][4];
    #pragma unroll
    for (int m = 0; m < 8; ++m)
        #pragma unroll
        for (int n = 0; n < 4; ++n) acc[m][n] = f32x4{0.f, 0.f, 0.f, 0.f};

#define STAGE_A(tt, d)                                                        \
    {                                                                         \
        _Pragma("unroll")                                                     \
        for (int h = 0; h < 2; ++h) {                                         \
            const __hip_bfloat16* src =                                       \
                A + (m0 + h * 128 + srowoff) * 1024 + (tt) * 32 + skel;       \
            gload_lds16(src, lds + (d) * 16384 + (h * 512 + tid) * 8);        \
        }                                                                     \
    }
#define STAGE_B(tt, d)                                                        \
    {                                                                         \
        _Pragma("unroll")                                                     \
        for (int h = 0; h < 2; ++h) {                                         \
            const __hip_bfloat16* src =                                       \
                Bw + (n0 + h * 128 + srowoff) * 1024 + (tt) * 32 + skel;      \
            gload_lds16(src, lds + (d) * 16384 + 8192 + (h * 512 + tid) * 8); \
        }                                                                     \
    }

    STAGE_A(0, 0); STAGE_B(0, 0);
    STAGE_A(1, 1); STAGE_B(1, 1);
    asm volatile("s_waitcnt vmcnt(4)" ::: "memory");
    __builtin_amdgcn_s_barrier();

    const int NT = 32;
    for (int t = 0; t < NT; ++t) {
        const int d = t % 3;
        const char* bufA = (const char*)(lds + d * 16384);
        const char* bufB = (const char*)(lds + d * 16384 + 8192);
        const int dn = (t + 2) % 3;
        const bool st = (t + 2 < NT);

        bf16x8 af[8], bfr0, bfr1;
        #pragma unroll
        for (int m = 0; m < 8; ++m) {
            int row = wr * 64 + m * 8 + (c >> 1);
            af[m] = *(const bf16x8*)(bufA + row * 128 + xterm);
        }
        {
            int row0 = wc * 32 + 0 * 8 + (c >> 1);
            int row1 = wc * 32 + 1 * 8 + (c >> 1);
            bfr0 = *(const bf16x8*)(bufB + row0 * 128 + xterm);
            bfr1 = *(const bf16x8*)(bufB + row1 * 128 + xterm);
        }
        if (st) STAGE_A(t + 2, dn);
        __builtin_amdgcn_s_barrier();
        asm volatile("s_waitcnt lgkmcnt(0)" ::: "memory");
        __builtin_amdgcn_sched_barrier(0);
        __builtin_amdgcn_s_setprio(1);
        #pragma unroll
        for (int m = 0; m < 8; ++m) {
            acc[m][0] = MFMA16(af[m], bfr0, acc[m][0]);
            acc[m][1] = MFMA16(af[m], bfr1, acc[m][1]);
        }
        __builtin_amdgcn_s_setprio(0);
        __builtin_amdgcn_s_barrier();

        {
            int row2 = wc * 32 + 2 * 8 + (c >> 1);
            int row3 = wc * 32 + 3 * 8 + (c >> 1);
            bfr0 = *(const bf16x8*)(bufB + row2 * 128 + xterm);
            bfr1 = *(const bf16x8*)(bufB + row3 * 128 + xterm);
        }
        if (st) STAGE_B(t + 2, dn);
        __builtin_amdgcn_s_barrier();
        if (t < NT - 2)
            asm volatile("s_waitcnt vmcnt(4)" ::: "memory");
        else if (t == NT - 2)
            asm volatile("s_waitcnt vmcnt(0)" ::: "memory");
        asm volatile("s_waitcnt lgkmcnt(0)" ::: "memory");
        __builtin_amdgcn_sched_barrier(0);
        __builtin_amdgcn_s_setprio(1);
        #pragma unroll
        for (int m = 0; m < 8; ++m) {
            acc[m][2] = MFMA16(af[m], bfr0, acc[m][2]);
            acc[m][3] = MFMA16(af[m], bfr1, acc[m][3]);
        }
        __builtin_amdgcn_s_setprio(0);
        __builtin_amdgcn_s_barrier();
    }
#undef STAGE_A
#undef STAGE_B

    #pragma unroll
    for (int m = 0; m < 8; ++m) {
        #pragma unroll
        for (int n = 0; n < 4; ++n) {
            long col = n0 + wc * 64 + n * 16 + c;
            float bv = bias[col];
            #pragma unroll
            for (int r = 0; r < 4; ++r) {
                long row = m0 + wr * 128 + m * 16 + g * 4 + r;
                C[row * 3072 + col] = __float2bfloat16(acc[m][n][r] + bv);
            }
        }
    }
}

// ---------------- NT GEMM (out-proj): 128 x (NF*32) tile ----------------
template<int BF16_OUT, int NF>
__global__ __launch_bounds__(256, 2)
void gemm_nt(const __hip_bfloat16* __restrict__ A,
             const __hip_bfloat16* __restrict__ Bw,
             const float* __restrict__ bias,
             void* __restrict__ Cv,
             int M, int N, int K) {
    __shared__ short sA[128 * 64];
    __shared__ short sB[NF * 32 * 64];
    const int tid = threadIdx.x;
    const int wave = tid >> 6, lane = tid & 63;
    const int g = lane >> 4, c = lane & 15;
    const int wr = wave >> 1, wc = wave & 1;
    const long m0 = (long)blockIdx.y * 128, n0 = (long)blockIdx.x * (NF * 32);

    f32x4 acc[4][NF];
    #pragma unroll
    for (int m = 0; m < 4; ++m)
        #pragma unroll
        for (int n = 0; n < NF; ++n) acc[m][n] = f32x4{0.f, 0.f, 0.f, 0.f};

    for (int k0 = 0; k0 < K; k0 += 64) {
        #pragma unroll
        for (int i = 0; i < 4; ++i) {
            int cb = (i * 4 + wave) * 64;
            int chunk = cb + lane;
            int row = chunk >> 3;
            int sc = ((chunk & 7) * 16) ^ ((row & 7) << 4);
            const char* gA = (const char*)(A + (m0 + row) * (long)K + k0) + sc;
            gload_lds16(gA, (char*)sA + cb * 16);
        }
        #pragma unroll
        for (int i = 0; i < NF; ++i) {
            int cb = (i * 4 + wave) * 64;
            int chunk = cb + lane;
            int row = chunk >> 3;
            int sc = ((chunk & 7) * 16) ^ ((row & 7) << 4);
            const char* gB = (const char*)(Bw + (n0 + row) * (long)K + k0) + sc;
            gload_lds16(gB, (char*)sB + cb * 16);
        }
        __syncthreads();
        #pragma unroll
        for (int s = 0; s < 2; ++s) {
            bf16x8 af[4], bfr[NF];
            #pragma unroll
            for (int m = 0; m < 4; ++m) {
                int row = wr * 64 + m * 16 + c;
                int kb = (s * 64 + g * 16) ^ ((row & 7) << 4);
                af[m] = *(const bf16x8*)((const char*)sA + row * 128 + kb);
            }
            #pragma unroll
            for (int n = 0; n < NF; ++n) {
                int row = wc * (NF * 16) + n * 16 + c;
                int kb = (s * 64 + g * 16) ^ ((row & 7) << 4);
                bfr[n] = *(const bf16x8*)((const char*)sB + row * 128 + kb);
            }
            #pragma unroll
            for (int m = 0; m < 4; ++m)
                #pragma unroll
                for (int n = 0; n < NF; ++n)
                    acc[m][n] = MFMA16(af[m], bfr[n], acc[m][n]);
        }
        __syncthreads();
    }

    #pragma unroll
    for (int m = 0; m < 4; ++m) {
        #pragma unroll
        for (int n = 0; n < NF; ++n) {
            long col = n0 + wc * (NF * 16) + n * 16 + c;
            float bv = bias[col];
            #pragma unroll
            for (int r = 0; r < 4; ++r) {
                long row = m0 + wr * 64 + m * 16 + g * 4 + r;
                float v = acc[m][n][r] + bv;
                if (BF16_OUT)
                    ((__hip_bfloat16*)Cv)[row * N + col] = __float2bfloat16(v);
                else
                    ((float*)Cv)[row * N + col] = v;
            }
        }
    }
}

// ---------------- attention v4: lagged-PV pipeline (T15) ----------------
// P(t) written at iter t, consumed at iter t+1; iteration barrier is the
// landing fence (no explicit lgkm stall). V: 3-buffer ring; P: per-wave 2-buf.
// All P/V LDS tiles XOR-16B swizzled (no padding).

__device__ __forceinline__ void softmax_store(
    const f32x4 (&accs)[4], const float (&ab)[4][4], float (&m)[4],
    f32x4& accL, f32x4 (&acc_o)[4], short* sPw,
    float scale, int qi0, int kv0, bool diag, int g, int c)
{
    float s[4][4], pmax[4];
    bool ok = true;
    #pragma unroll
    for (int r = 0; r < 4; ++r) {
        int qi = qi0 + r;
        #pragma unroll
        for (int nf = 0; nf < 4; ++nf) {
            float sv = fmaf(accs[nf][r], scale, ab[nf][r]);
            if (diag && (kv0 + nf * 16 + c > qi)) sv = -1e30f;
            s[r][nf] = sv;
        }
        pmax[r] = fmaxf(fmaxf(s[r][0], s[r][1]), fmaxf(s[r][2], s[r][3]));
        ok = ok && (pmax[r] <= m[r] + 8.0f);
    }
    if (!__all(ok)) {   // rare after first tile
        #pragma unroll
        for (int r = 0; r < 4; ++r) {
            float mx = pmax[r];
            mx = fmaxf(mx, __shfl_xor(mx, 1));
            mx = fmaxf(mx, __shfl_xor(mx, 2));
            mx = fmaxf(mx, __shfl_xor(mx, 4));
            mx = fmaxf(mx, __shfl_xor(mx, 8));
            float mn = fmaxf(m[r], mx);
            float alpha = __expf(m[r] - mn);
            m[r] = mn;
            accL[r] *= alpha;
            #pragma unroll
            for (int d = 0; d < 4; ++d) acc_o[d][r] *= alpha;
        }
    }
    #pragma unroll
    for (int r = 0; r < 4; ++r) {
        int row = g * 4 + r;
        #pragma unroll
        for (int nf = 0; nf < 4; ++nf)
            *(short*)((char*)sPw + row * 128 +
                      ((nf * 32 + c * 2) ^ ((row & 7) << 4))) =
                f2bf(__expf(s[r][nf] - m[r]));
    }
}

__device__ __forceinline__ void pv_accum(
    const short* sPw, const short* sVtc,
    f32x4 (&acc_o)[4], f32x4& accL, int g, int c)
{
    const int cs = (c & 7) << 4;
    bf16x8 pf0 = *(const bf16x8*)((const char*)sPw + c * 128 + ((g * 16) ^ cs));
    bf16x8 pf1 = *(const bf16x8*)((const char*)sPw + c * 128 + ((64 + g * 16) ^ cs));
    const short ONE = 0x3F80;
    const bf16x8 ones = {ONE, ONE, ONE, ONE, ONE, ONE, ONE, ONE};
    accL = MFMA16(pf0, ones, accL);
    accL = MFMA16(pf1, ones, accL);
    #pragma unroll
    for (int d = 0; d < 4; ++d) {
        const char* vb = (const char*)sVtc + (d * 16 + c) * 128;   // (d*16+c)&7 == c&7
        bf16x8 vf0 = *(const bf16x8*)(vb + ((g * 16) ^ cs));
        bf16x8 vf1 = *(const bf16x8*)(vb + ((64 + g * 16) ^ cs));
        acc_o[d] = MFMA16(pf0, vf0, acc_o[d]);
        acc_o[d] = MFMA16(pf1, vf1, acc_o[d]);
    }
}

__global__ __launch_bounds__(256, 2)
void attn_kernel(const __hip_bfloat16* __restrict__ qkv,
                 const float* __restrict__ alibi,
                 const float* __restrict__ scales,
                 __hip_bfloat16* __restrict__ out) {
    __shared__ short sK[2][64 * 64];        // 16 KB, swizzled (gload staging)
    __shared__ short sVt[3][64 * 64];       // 24 KB ring, XOR-swizzled
    __shared__ short sPB[4][2][16 * 64];    // 16 KB per-wave double-buf
    __shared__ short sPA[4][2][16 * 64];    // 16 KB

    const int p = blockIdx.x, h = blockIdx.y, b = blockIdx.z;
    const int qtA = p, qtB = 31 - p;
    const int nIter = qtB + 1;
    const int tid = threadIdx.x;
    const int wave = tid >> 6, lane = tid & 63;
    const int g = lane >> 4, c = lane & 15;
    const float scale = scales[b];
    const long base_bl = (long)b * 2048;

    const int qA0 = qtA * 64 + wave * 16;
    const int qB0 = qtB * 64 + wave * 16;

    const __hip_bfloat16* qrowA = qkv + (base_bl + qA0 + c) * 3072 + h * 64;
    const __hip_bfloat16* qrowB = qkv + (base_bl + qB0 + c) * 3072 + h * 64;
    bf16x8 qAf0 = *(const bf16x8*)(qrowA + g * 8);
    bf16x8 qAf1 = *(const bf16x8*)(qrowA + 32 + g * 8);
    bf16x8 qBf0 = *(const bf16x8*)(qrowB + g * 8);
    bf16x8 qBf1 = *(const bf16x8*)(qrowB + 32 + g * 8);

    const __hip_bfloat16* kg = qkv + base_bl * 3072 + 1024 + h * 64;
    const __hip_bfloat16* vg = qkv + base_bl * 3072 + 2048 + h * 64;
    const float* abA_base = alibi + (long)h * 2048 * 2048 + (long)(qA0 + g * 4) * 2048;
    const float* abB_base = alibi + (long)h * 2048 * 2048 + (long)(qB0 + g * 4) * 2048;

    const int p2 = tid & 31;
    const int d0 = (tid >> 5) * 8;
    const __hip_bfloat16* vrow = vg + (long)(2 * p2) * 3072 + d0;

    f32x4 accA[4], accB[4], accLA, accLB;
    float mA[4], mB[4];
    #pragma unroll
    for (int d = 0; d < 4; ++d) {
        accA[d] = f32x4{0.f, 0.f, 0.f, 0.f};
        accB[d] = f32x4{0.f, 0.f, 0.f, 0.f};
    }
    accLA = f32x4{0.f, 0.f, 0.f, 0.f};
    accLB = f32x4{0.f, 0.f, 0.f, 0.f};
    #pragma unroll
    for (int r = 0; r < 4; ++r) { mA[r] = -3e38f; mB[r] = -3e38f; }

    float abA[4][4], abB[4][4], abAn[4][4], abBn[4][4];

    // prologue: stage K(0), V(0), ab(0)
    {
        #pragma unroll
        for (int i = 0; i < 2; ++i) {
            int cb = (i * 4 + wave) * 64;
            int chunk = cb + lane;
            int row = chunk >> 3;
            int sc = ((chunk & 7) * 16) ^ ((row & 7) << 4);
            gload_lds16((const char*)(kg + (long)row * 3072) + sc,
                        (char*)sK[0] + cb * 16);
        }
        bf16x8 va = *(const bf16x8*)vrow;
        bf16x8 vb = *(const bf16x8*)(vrow + 3072);
        #pragma unroll
        for (int j = 0; j < 8; ++j) {
            int row = d0 + j;
            unsigned pk = ((unsigned)(unsigned short)va[j]) |
                          (((unsigned)(unsigned short)vb[j]) << 16);
            *(unsigned*)((char*)sVt[0] + row * 128 +
                         ((p2 * 4) ^ ((row & 7) << 4))) = pk;
        }
        #pragma unroll
        for (int nf = 0; nf < 4; ++nf)
            #pragma unroll
            for (int r = 0; r < 4; ++r) {
                abA[nf][r] = abA_base[(long)r * 2048 + nf * 16 + c];
                abB[nf][r] = abB_base[(long)r * 2048 + nf * 16 + c];
                abAn[nf][r] = 0.f; abBn[nf][r] = 0.f;
            }
    }
    __syncthreads();

    for (int t = 0; t < nIter; ++t) {
        const int kv0 = t * 64;
        const bool haveNext = (t + 1 < nIter);
        const bool dualT = (t <= qtA);
        bf16x8 va, vb;

        if (haveNext) {
            // issue next K tile (direct to LDS) + next V loads (regs, write late)
            #pragma unroll
            for (int i = 0; i < 2; ++i) {
                int cb = (i * 4 + wave) * 64;
                int chunk = cb + lane;
                int row = chunk >> 3;
                int sc = ((chunk & 7) * 16) ^ ((row & 7) << 4);
                gload_lds16((const char*)(kg + (long)(kv0 + 64 + row) * 3072) + sc,
                            (char*)sK[(t + 1) & 1] + cb * 16);
            }
            const __hip_bfloat16* vp = vrow + (long)(kv0 + 64) * 3072;
            va = *(const bf16x8*)vp;
            vb = *(const bf16x8*)(vp + 3072);
            #pragma unroll
            for (int nf = 0; nf < 4; ++nf)
                #pragma unroll
                for (int r = 0; r < 4; ++r)
                    abBn[nf][r] = abB_base[(long)r * 2048 + kv0 + 64 + nf * 16 + c];
        }
        if (t + 1 <= qtA) {
            #pragma unroll
            for (int nf = 0; nf < 4; ++nf)
                #pragma unroll
                for (int r = 0; r < 4; ++r)
                    abAn[nf][r] = abA_base[(long)r * 2048 + kv0 + 64 + nf * 16 + c];
        }

        // K fragments from current buffer
        bf16x8 kf[4][2];
        const int swz = (c & 7) << 4;
        #pragma unroll
        for (int nf = 0; nf < 4; ++nf) {
            const char* kb = (const char*)sK[t & 1] + (nf * 16 + c) * 128;
            kf[nf][0] = *(const bf16x8*)(kb + ((g * 16) ^ swz));
            kf[nf][1] = *(const bf16x8*)(kb + ((64 + g * 16) ^ swz));
        }

        // QK for B, then lagged PV(t-1), then softmax B
        f32x4 accsB[4];
        __builtin_amdgcn_s_setprio(1);
        #pragma unroll
        for (int nf = 0; nf < 4; ++nf) {
            accsB[nf] = f32x4{0.f, 0.f, 0.f, 0.f};
            accsB[nf] = MFMA16(qBf0, kf[nf][0], accsB[nf]);
            accsB[nf] = MFMA16(qBf1, kf[nf][1], accsB[nf]);
        }
        if (t >= 1) {
            const short* sVp = sVt[(t - 1) % 3];
            pv_accum(&sPB[wave][(t - 1) & 1][0], sVp, accB, accLB, g, c);
            if (t - 1 <= qtA)
                pv_accum(&sPA[wave][(t - 1) & 1][0], sVp, accA, accLA, g, c);
        }
        __builtin_amdgcn_s_setprio(0);

        softmax_store(accsB, abB, mB, accLB, accB, &sPB[wave][t & 1][0],
                      scale, qB0 + g * 4, kv0, t == qtB, g, c);

        if (dualT) {
            f32x4 accsA[4];
            __builtin_amdgcn_s_setprio(1);
            #pragma unroll
            for (int nf = 0; nf < 4; ++nf) {
                accsA[nf] = f32x4{0.f, 0.f, 0.f, 0.f};
                accsA[nf] = MFMA16(qAf0, kf[nf][0], accsA[nf]);
                accsA[nf] = MFMA16(qAf1, kf[nf][1], accsA[nf]);
            }
            __builtin_amdgcn_s_setprio(0);
            softmax_store(accsA, abA, mA, accLA, accA, &sPA[wave][t & 1][0],
                          scale, qA0 + g * 4, kv0, t == qtA, g, c);
        }

        if (haveNext) {
            char* sVn = (char*)sVt[(t + 1) % 3];
            #pragma unroll
            for (int j = 0; j < 8; ++j) {
                int row = d0 + j;
                unsigned pk = ((unsigned)(unsigned short)va[j]) |
                              (((unsigned)(unsigned short)vb[j]) << 16);
                *(unsigned*)(sVn + row * 128 + ((p2 * 4) ^ ((row & 7) << 4))) = pk;
            }
        }
        __syncthreads();
        #pragma unroll
        for (int nf = 0; nf < 4; ++nf)
            #pragma unroll
            for (int r = 0; r < 4; ++r) {
                abA[nf][r] = abAn[nf][r];
                abB[nf][r] = abBn[nf][r];
            }
    }

    // epilogue: drain last B tile's PV (A's last PV already ran in-loop)
    pv_accum(&sPB[wave][(nIter - 1) & 1][0], sVt[(nIter - 1) % 3],
             accB, accLB, g, c);

    __hip_bfloat16* opA = out + (base_bl + qA0 + g * 4) * 1024 + h * 64;
    __hip_bfloat16* opB = out + (base_bl + qB0 + g * 4) * 1024 + h * 64;
    #pragma unroll
    for (int r = 0; r < 4; ++r) {
        float invA = 1.0f / accLA[r];
        float invB = 1.0f / accLB[r];
        #pragma unroll
        for (int d = 0; d < 4; ++d) {
            opA[(long)r * 1024 + d * 16 + c] = __float2bfloat16(accA[d][r] * invA);
            opB[(long)r * 1024 + d * 16 + c] = __float2bfloat16(accB[d][r] * invB);
        }
    }
}

extern "C" void kernel_launch(void* const* d_in, const int* in_sizes, int n_in,
                              void* d_out, int out_size, void* d_ws, size_t ws_size,
                              hipStream_t stream) {
    const float* x      = (const float*)d_in[0];
    const float* phylo  = (const float*)d_in[1];
    const float* alibi  = (const float*)d_in[2];
    const float* qkv_w  = (const float*)d_in[4];
    const float* qkv_b  = (const float*)d_in[5];
    const float* out_w  = (const float*)d_in[6];
    const float* out_b  = (const float*)d_in[7];
    const float* alphap = (const float*)d_in[8];

    char* ws = (char*)d_ws;
    __hip_bfloat16* xbf   = (__hip_bfloat16*)(ws);                 // 8 MB
    __hip_bfloat16* qwbf  = (__hip_bfloat16*)(ws + (8l << 20));    // 6 MB
    __hip_bfloat16* owbf  = (__hip_bfloat16*)(ws + (14l << 20));   // 2 MB
    __hip_bfloat16* qkvbf = (__hip_bfloat16*)(ws + (16l << 20));   // 24 MB
    __hip_bfloat16* aobf  = (__hip_bfloat16*)(ws + (40l << 20));   // 8 MB
    float* scales         = (float*)(ws + (48l << 20));            // 2 floats

    (void)hipFuncSetAttribute((const void*)gemm_qkv_8ph,
                              hipFuncAttributeMaxDynamicSharedMemorySize, 98304);

    prep_kernel<<<2050, 256, 0, stream>>>(x, qkv_w, out_w, phylo, alphap,
                                          (s4v*)xbf, (s4v*)qwbf, (s4v*)owbf, scales);

    gemm_qkv_8ph<<<dim3(12, 16), 512, 98304, stream>>>(xbf, qwbf, qkv_b, qkvbf);
    attn_kernel<<<dim3(16, 16, 2), 256, 0, stream>>>(qkvbf, alibi, scales, aobf);
    gemm_nt<0, 2><<<dim3(16, 32), 256, 0, stream>>>(aobf, owbf, out_b, d_out,
                                                    4096, 1024, 1024);
}

// Round 6
// 128.466 us; speedup vs baseline: 1.8717x; 1.8717x over previous
//
#include <hip/hip_runtime.h>
#include <hip/hip_bf16.h>

typedef __attribute__((ext_vector_type(8))) short bf16x8;
typedef __attribute__((ext_vector_type(4))) float f32x4;
typedef __attribute__((ext_vector_type(4))) float f4v;
typedef __attribute__((ext_vector_type(4))) short s4v;

__device__ __forceinline__ short f2bf(float f) {
    union { __hip_bfloat16 h; short s; } u;
    u.h = __float2bfloat16(f);
    return u.s;
}

__device__ __forceinline__ void gload_lds16(const void* g, void* l) {
    __builtin_amdgcn_global_load_lds(
        (const __attribute__((address_space(1))) void*)g,
        (__attribute__((address_space(3))) void*)l,
        16, 0, 0);
}

#define MFMA16(a, b, c) __builtin_amdgcn_mfma_f32_16x16x32_bf16((a), (b), (c), 0, 0, 0)

// ---------------- fused prep: 3x f32->bf16 cvt + per-batch scale ----------------
__global__ void prep_kernel(const float* __restrict__ x,
                            const float* __restrict__ qw,
                            const float* __restrict__ ow,
                            const float* __restrict__ pd,
                            const float* __restrict__ alphap,
                            s4v* __restrict__ xb, s4v* __restrict__ qb,
                            s4v* __restrict__ ob, float* __restrict__ scales) {
    __shared__ float wsum[4];
    if (blockIdx.x >= 2048) {
        int b = blockIdx.x - 2048;
        float s = 0.f;
        for (int i = threadIdx.x; i < 2048; i += 256) s += pd[b * 2048 + i];
        for (int o = 32; o; o >>= 1) s += __shfl_down(s, o);
        if ((threadIdx.x & 63) == 0) wsum[threadIdx.x >> 6] = s;
        __syncthreads();
        if (threadIdx.x == 0) {
            float t = wsum[0] + wsum[1] + wsum[2] + wsum[3];
            float mean = t * (1.0f / 2048.0f);
            float temp = fmaxf(1.0f + alphap[0] * mean, 1e-6f);
            scales[b] = 0.125f * temp;
        }
        return;
    }
    #pragma unroll
    for (int j = 0; j < 4; ++j) {
        int idx = blockIdx.x * 1024 + j * 256 + threadIdx.x;
        const f4v* src;
        s4v* dst;
        int off;
        if (idx < 1048576)      { src = (const f4v*)x;  dst = xb; off = idx; }
        else if (idx < 1835008) { src = (const f4v*)qw; dst = qb; off = idx - 1048576; }
        else                    { src = (const f4v*)ow; dst = ob; off = idx - 1835008; }
        f4v v = src[off];
        s4v o;
        #pragma unroll
        for (int k = 0; k < 4; ++k) o[k] = f2bf(v[k]);
        dst[off] = o;
    }
}

// ---------------- NT GEMM: C[M,N] = A[M,K] * B[N,K]^T + bias ----------------
template<int BF16_OUT, int NF>
__global__ __launch_bounds__(256, 2)
void gemm_nt(const __hip_bfloat16* __restrict__ A,
             const __hip_bfloat16* __restrict__ Bw,
             const float* __restrict__ bias,
             void* __restrict__ Cv,
             int M, int N, int K) {
    __shared__ short sA[128 * 64];
    __shared__ short sB[NF * 32 * 64];
    const int tid = threadIdx.x;
    const int wave = tid >> 6, lane = tid & 63;
    const int g = lane >> 4, c = lane & 15;
    const int wr = wave >> 1, wc = wave & 1;
    const long m0 = (long)blockIdx.y * 128, n0 = (long)blockIdx.x * (NF * 32);

    f32x4 acc[4][NF];
    #pragma unroll
    for (int m = 0; m < 4; ++m)
        #pragma unroll
        for (int n = 0; n < NF; ++n) acc[m][n] = f32x4{0.f, 0.f, 0.f, 0.f};

    for (int k0 = 0; k0 < K; k0 += 64) {
        #pragma unroll
        for (int i = 0; i < 4; ++i) {
            int cb = (i * 4 + wave) * 64;
            int chunk = cb + lane;
            int row = chunk >> 3;
            int sc = ((chunk & 7) * 16) ^ ((row & 7) << 4);
            const char* gA = (const char*)(A + (m0 + row) * (long)K + k0) + sc;
            gload_lds16(gA, (char*)sA + cb * 16);
        }
        #pragma unroll
        for (int i = 0; i < NF; ++i) {
            int cb = (i * 4 + wave) * 64;
            int chunk = cb + lane;
            int row = chunk >> 3;
            int sc = ((chunk & 7) * 16) ^ ((row & 7) << 4);
            const char* gB = (const char*)(Bw + (n0 + row) * (long)K + k0) + sc;
            gload_lds16(gB, (char*)sB + cb * 16);
        }
        __syncthreads();
        #pragma unroll
        for (int s = 0; s < 2; ++s) {
            bf16x8 af[4], bfr[NF];
            #pragma unroll
            for (int m = 0; m < 4; ++m) {
                int row = wr * 64 + m * 16 + c;
                int kb = (s * 64 + g * 16) ^ ((row & 7) << 4);
                af[m] = *(const bf16x8*)((const char*)sA + row * 128 + kb);
            }
            #pragma unroll
            for (int n = 0; n < NF; ++n) {
                int row = wc * (NF * 16) + n * 16 + c;
                int kb = (s * 64 + g * 16) ^ ((row & 7) << 4);
                bfr[n] = *(const bf16x8*)((const char*)sB + row * 128 + kb);
            }
            #pragma unroll
            for (int m = 0; m < 4; ++m)
                #pragma unroll
                for (int n = 0; n < NF; ++n)
                    acc[m][n] = MFMA16(af[m], bfr[n], acc[m][n]);
        }
        __syncthreads();
    }

    #pragma unroll
    for (int m = 0; m < 4; ++m) {
        #pragma unroll
        for (int n = 0; n < NF; ++n) {
            long col = n0 + wc * (NF * 16) + n * 16 + c;
            float bv = bias[col];
            #pragma unroll
            for (int r = 0; r < 4; ++r) {
                long row = m0 + wr * 64 + m * 16 + g * 4 + r;
                float v = acc[m][n][r] + bv;
                if (BF16_OUT)
                    ((__hip_bfloat16*)Cv)[row * N + col] = __float2bfloat16(v);
                else
                    ((float*)Cv)[row * N + col] = v;
            }
        }
    }
}

// ---------------- attention v5: unpaired q-tiles, longest-first ----------------
// 1024 blocks (qt,h,b); 4 waves x 16 q-rows; KVBLK=64 double-buffered;
// alibi reg-prefetch 1 iter ahead; defer-max softmax; ones-MFMA row-sum;
// async V write-late. LDS 43KB -> 3 blocks/CU; VGPR capped at 128.

__device__ __forceinline__ void compute_tile(
    const short* sKc, const short* sVtc, short* sPw,
    bf16x8 qf0, bf16x8 qf1,
    f32x4 (&acc_o)[4], f32x4& accL, float (&m)[4],
    const float (&ab)[4][4],
    float scale, int qi0, int kv0, bool diag, int g, int c)
{
    f32x4 accs[4];
    const int swz = (c & 7) << 4;
    __builtin_amdgcn_s_setprio(1);
    #pragma unroll
    for (int nf = 0; nf < 4; ++nf) {
        const char* kb = (const char*)sKc + (nf * 16 + c) * 128;
        bf16x8 kf0 = *(const bf16x8*)(kb + ((g * 16) ^ swz));
        bf16x8 kf1 = *(const bf16x8*)(kb + ((64 + g * 16) ^ swz));
        accs[nf] = f32x4{0.f, 0.f, 0.f, 0.f};
        accs[nf] = MFMA16(qf0, kf0, accs[nf]);
        accs[nf] = MFMA16(qf1, kf1, accs[nf]);
    }
    __builtin_amdgcn_s_setprio(0);
    float s[4][4], pmax[4];
    bool ok = true;
    #pragma unroll
    for (int r = 0; r < 4; ++r) {
        int qi = qi0 + r;
        #pragma unroll
        for (int nf = 0; nf < 4; ++nf) {
            float sv = fmaf(accs[nf][r], scale, ab[nf][r]);
            if (diag && (kv0 + nf * 16 + c > qi)) sv = -1e30f;
            s[r][nf] = sv;
        }
        pmax[r] = fmaxf(fmaxf(s[r][0], s[r][1]), fmaxf(s[r][2], s[r][3]));
        ok = ok && (pmax[r] <= m[r] + 8.0f);
    }
    if (!__all(ok)) {   // rare after first tile
        #pragma unroll
        for (int r = 0; r < 4; ++r) {
            float mx = pmax[r];
            mx = fmaxf(mx, __shfl_xor(mx, 1));
            mx = fmaxf(mx, __shfl_xor(mx, 2));
            mx = fmaxf(mx, __shfl_xor(mx, 4));
            mx = fmaxf(mx, __shfl_xor(mx, 8));
            float mn = fmaxf(m[r], mx);
            float alpha = __expf(m[r] - mn);
            m[r] = mn;
            accL[r] *= alpha;
            #pragma unroll
            for (int d = 0; d < 4; ++d) acc_o[d][r] *= alpha;
        }
    }
    #pragma unroll
    for (int r = 0; r < 4; ++r)
        #pragma unroll
        for (int nf = 0; nf < 4; ++nf)
            sPw[(g * 4 + r) * 72 + nf * 16 + c] = f2bf(__expf(s[r][nf] - m[r]));
    asm volatile("s_waitcnt lgkmcnt(0)" ::: "memory");
    bf16x8 pf0 = *(const bf16x8*)((const char*)sPw + c * 144 + g * 16);
    bf16x8 pf1 = *(const bf16x8*)((const char*)sPw + c * 144 + 64 + g * 16);
    const short ONE = 0x3F80;
    const bf16x8 ones = {ONE, ONE, ONE, ONE, ONE, ONE, ONE, ONE};
    __builtin_amdgcn_s_setprio(1);
    accL = MFMA16(pf0, ones, accL);
    accL = MFMA16(pf1, ones, accL);
    #pragma unroll
    for (int d = 0; d < 4; ++d) {
        const char* vb = (const char*)sVtc + (d * 16 + c) * 144;
        bf16x8 vf0 = *(const bf16x8*)(vb + g * 16);
        bf16x8 vf1 = *(const bf16x8*)(vb + 64 + g * 16);
        acc_o[d] = MFMA16(pf0, vf0, acc_o[d]);
        acc_o[d] = MFMA16(pf1, vf1, acc_o[d]);
    }
    __builtin_amdgcn_s_setprio(0);
}

__global__ __launch_bounds__(256, 4)
void attn_kernel(const __hip_bfloat16* __restrict__ qkv,   // [B*L, 3072]
                 const float* __restrict__ alibi,          // [H, L, L]
                 const float* __restrict__ scales,         // [B]
                 __hip_bfloat16* __restrict__ out) {       // [B*L, 1024]
    __shared__ short sK[2][64 * 64];      // 16 KB, swizzled staging
    __shared__ short sVt[2][64 * 72];     // 18 KB, [64 d][64 kv + 8 pad]
    __shared__ short sP[4][16 * 72];      // 9 KB, per-wave

    const int h = blockIdx.x, b = blockIdx.y;
    const int qt = 31 - blockIdx.z;       // longest q-tiles dispatched first
    const int nIter = qt + 1;
    const int tid = threadIdx.x;
    const int wave = tid >> 6, lane = tid & 63;
    const int g = lane >> 4, c = lane & 15;
    const float scale = scales[b];
    const long base_bl = (long)b * 2048;

    const int q0 = qt * 64 + wave * 16;

    const __hip_bfloat16* qrow = qkv + (base_bl + q0 + c) * 3072 + h * 64;
    bf16x8 qf0 = *(const bf16x8*)(qrow + g * 8);
    bf16x8 qf1 = *(const bf16x8*)(qrow + 32 + g * 8);

    const __hip_bfloat16* kg = qkv + base_bl * 3072 + 1024 + h * 64;
    const __hip_bfloat16* vg = qkv + base_bl * 3072 + 2048 + h * 64;
    const float* ab_base = alibi + (long)h * 2048 * 2048 + (long)(q0 + g * 4) * 2048;

    const int p2 = tid & 31;
    const int d0 = (tid >> 5) * 8;
    const __hip_bfloat16* vrow = vg + (long)(2 * p2) * 3072 + d0;

    f32x4 acc[4], accL;
    float m[4];
    #pragma unroll
    for (int d = 0; d < 4; ++d) acc[d] = f32x4{0.f, 0.f, 0.f, 0.f};
    accL = f32x4{0.f, 0.f, 0.f, 0.f};
    #pragma unroll
    for (int r = 0; r < 4; ++r) m[r] = -3e38f;

    float ab[4][4], abn[4][4];

    // prologue: stage K(0), V(0), ab(0)
    {
        #pragma unroll
        for (int i = 0; i < 2; ++i) {
            int cb = (i * 4 + wave) * 64;
            int chunk = cb + lane;
            int row = chunk >> 3;
            int sc = ((chunk & 7) * 16) ^ ((row & 7) << 4);
            gload_lds16((const char*)(kg + (long)row * 3072) + sc,
                        (char*)sK[0] + cb * 16);
        }
        bf16x8 va = *(const bf16x8*)vrow;
        bf16x8 vb = *(const bf16x8*)(vrow + 3072);
        #pragma unroll
        for (int j = 0; j < 8; ++j) {
            unsigned pk = ((unsigned)(unsigned short)va[j]) |
                          (((unsigned)(unsigned short)vb[j]) << 16);
            *(unsigned*)((char*)sVt[0] + (d0 + j) * 144 + p2 * 4) = pk;
        }
        #pragma unroll
        for (int nf = 0; nf < 4; ++nf)
            #pragma unroll
            for (int r = 0; r < 4; ++r) {
                ab[nf][r] = ab_base[(long)r * 2048 + nf * 16 + c];
                abn[nf][r] = 0.f;
            }
    }
    __syncthreads();

    for (int t = 0; t < nIter; ++t) {
        const int cur = t & 1;
        const int kv0 = t * 64;
        bf16x8 va, vb;
        const bool haveNext = (t + 1 < nIter);
        if (haveNext) {
            // issue next K tile (direct to LDS) + next V loads (regs, write late)
            #pragma unroll
            for (int i = 0; i < 2; ++i) {
                int cb = (i * 4 + wave) * 64;
                int chunk = cb + lane;
                int row = chunk >> 3;
                int sc = ((chunk & 7) * 16) ^ ((row & 7) << 4);
                gload_lds16((const char*)(kg + (long)(kv0 + 64 + row) * 3072) + sc,
                            (char*)sK[cur ^ 1] + cb * 16);
            }
            const __hip_bfloat16* vp = vrow + (long)(kv0 + 64) * 3072;
            va = *(const bf16x8*)vp;
            vb = *(const bf16x8*)(vp + 3072);
            #pragma unroll
            for (int nf = 0; nf < 4; ++nf)
                #pragma unroll
                for (int r = 0; r < 4; ++r)
                    abn[nf][r] = ab_base[(long)r * 2048 + kv0 + 64 + nf * 16 + c];
        }

        compute_tile(sK[cur], sVt[cur], &sP[wave][0], qf0, qf1,
                     acc, accL, m, ab, scale, q0 + g * 4, kv0, t == qt, g, c);

        if (haveNext) {
            #pragma unroll
            for (int j = 0; j < 8; ++j) {
                unsigned pk = ((unsigned)(unsigned short)va[j]) |
                              (((unsigned)(unsigned short)vb[j]) << 16);
                *(unsigned*)((char*)sVt[cur ^ 1] + (d0 + j) * 144 + p2 * 4) = pk;
            }
        }
        __syncthreads();
        #pragma unroll
        for (int nf = 0; nf < 4; ++nf)
            #pragma unroll
            for (int r = 0; r < 4; ++r)
                ab[nf][r] = abn[nf][r];
    }

    __hip_bfloat16* op = out + (base_bl + q0 + g * 4) * 1024 + h * 64;
    #pragma unroll
    for (int r = 0; r < 4; ++r) {
        float inv = 1.0f / accL[r];
        #pragma unroll
        for (int d = 0; d < 4; ++d)
            op[(long)r * 1024 + d * 16 + c] = __float2bfloat16(acc[d][r] * inv);
    }
}

extern "C" void kernel_launch(void* const* d_in, const int* in_sizes, int n_in,
                              void* d_out, int out_size, void* d_ws, size_t ws_size,
                              hipStream_t stream) {
    const float* x      = (const float*)d_in[0];
    const float* phylo  = (const float*)d_in[1];
    const float* alibi  = (const float*)d_in[2];
    const float* qkv_w  = (const float*)d_in[4];
    const float* qkv_b  = (const float*)d_in[5];
    const float* out_w  = (const float*)d_in[6];
    const float* out_b  = (const float*)d_in[7];
    const float* alphap = (const float*)d_in[8];

    char* ws = (char*)d_ws;
    __hip_bfloat16* xbf   = (__hip_bfloat16*)(ws);                 // 8 MB
    __hip_bfloat16* qwbf  = (__hip_bfloat16*)(ws + (8l << 20));    // 6 MB
    __hip_bfloat16* owbf  = (__hip_bfloat16*)(ws + (14l << 20));   // 2 MB
    __hip_bfloat16* qkvbf = (__hip_bfloat16*)(ws + (16l << 20));   // 24 MB
    __hip_bfloat16* aobf  = (__hip_bfloat16*)(ws + (40l << 20));   // 8 MB
    float* scales         = (float*)(ws + (48l << 20));            // 2 floats

    prep_kernel<<<2050, 256, 0, stream>>>(x, qkv_w, out_w, phylo, alphap,
                                          (s4v*)xbf, (s4v*)qwbf, (s4v*)owbf, scales);

    gemm_nt<1, 4><<<dim3(24, 32), 256, 0, stream>>>(xbf, qwbf, qkv_b, qkvbf,
                                                    4096, 3072, 1024);
    attn_kernel<<<dim3(16, 2, 32), 256, 0, stream>>>(qkvbf, alibi, scales, aobf);
    gemm_nt<0, 2><<<dim3(16, 32), 256, 0, stream>>>(aobf, owbf, out_b, d_out,
                                                    4096, 1024, 1024);
}